// Round 8
// baseline (108.096 us; speedup 1.0000x reference)
//
#include <hip/hip_runtime.h>

#define NUM_CHR 24
#define N_EMB   512
#define DIM     512
#define BATCH   1024

#define T_SAMP     48   // samples per group: all ~43 of a chromosome in ONE group
#define GROUPS_CAP 2    // overflow safety to 96 samples/chrom (+8.3 sigma)
#define NSPLIT_N   8    // n-dimension split (partials)
#define NCHUNK     (N_EMB / NSPLIT_N)   // 64 rows per block
#define DSPLIT     2    // dim split (disjoint, no partials)
#define DSLICE     (DIM / DSPLIT)       // 256 floats
#define RCHUNK     8    // rows staged to LDS per chunk
#define NCHUNKS    (NCHUNK / RCHUNK)    // 8
#define WPAD       52   // wlT row stride (48 + 4)

// ---- workspace layout (bytes) ----
#define OFF_COUNTS 0u
#define OFF_LISTS  1024u                 // 24*1024 ints = 98304 B
#define OFF_W      99328u                // 1024*512 f32 = 2 MiB
#define OFF_P      2196480u              // NSPLIT_N * 2 MiB partials = 16 MiB
#define P_BYTES    ((size_t)BATCH * DIM * sizeof(float))

// ---------------- Kernel 1: RBF weights + chromosome bucketing ----------------
__global__ __launch_bounds__(256) void atac_weights_kernel(
    const int* __restrict__ chrom, const float* __restrict__ pos,
    const float* __restrict__ centers, const float* __restrict__ logvar,
    float* __restrict__ W, int* __restrict__ counts, int* __restrict__ lists) {
  const int b = blockIdx.x;
  const int tid = threadIdx.x;
  const int c = chrom[b];
  const float p = pos[b];
  const int n0 = tid;
  const int n1 = tid + 256;
  const float* cc = centers + (size_t)c * N_EMB;
  const float* lv = logvar + (size_t)c * N_EMB;

  const float d0 = p - cc[n0];
  const float d1 = p - cc[n1];
  const float w0 = expf(-(d0 * d0) / (2.0f * expf(lv[n0])));
  const float w1 = expf(-(d1 * d1) / (2.0f * expf(lv[n1])));

  float s = w0 + w1;
#pragma unroll
  for (int off = 32; off > 0; off >>= 1) s += __shfl_down(s, off);
  __shared__ float part[4];
  __shared__ float invtot;
  if ((tid & 63) == 0) part[tid >> 6] = s;
  __syncthreads();
  if (tid == 0) invtot = 1.0f / (part[0] + part[1] + part[2] + part[3]);
  __syncthreads();

  float* Wb = W + (size_t)b * N_EMB;
  const float it = invtot;
  Wb[n0] = w0 * it;
  Wb[n1] = w1 * it;

  if (tid == 0) {
    const int slot = atomicAdd(&counts[c], 1);
    lists[c * BATCH + slot] = b;
  }
}

// ---------------- Kernel 2: grouped weighted-sum, E read EXACTLY ONCE ----------
// Block (c, grp, z): z = zn + 8*zd. 48 samples (whole chromosome), n-rows
// [zn*64, zn*64+64), dims [zd*256, zd*256+256). Grid covers E disjointly ->
// each E element fetched once. 256 threads = 4 waves; wave sg owns 12 samples
// (sg*12..+11); lane owns 4 dims. E staged to LDS via global_load_lds
// (16B/lane, double-buffered, 8 rows/chunk). Latency self-covering: per chunk
// compute = 8 rows x (48 FMA x 2cyc + 4 LDS reads) ~ 960 cyc >= ~900 cyc DMA
// latency, independent of occupancy. Partials P[zn][sample][dim].
__global__ __launch_bounds__(256) void atac_reduce_kernel(
    const float* __restrict__ E, const float* __restrict__ W,
    const int* __restrict__ counts, const int* __restrict__ lists,
    float* __restrict__ P) {
  const int c = blockIdx.x;
  const int grp = blockIdx.y;
  const int zn = blockIdx.z & (NSPLIT_N - 1);
  const int zd = blockIdx.z >> 3;
  const int cnt = counts[c];
  const int base = grp * T_SAMP;
  if (base >= cnt) return;
  const int m = min(T_SAMP, cnt - base);
  const int tid = threadIdx.x;
  const int lane = tid & 63;
  const int sg = tid >> 6;        // wave index
  const int sb = sg * 12;         // first sample slot of this wave

  __shared__ int sidx[T_SAMP];
  __shared__ float wlT[NCHUNK][WPAD];        // [row][sample(48) + pad(4)]
  __shared__ float ebuf[2][RCHUNK][DSLICE];  // double-buffered E chunk (2 x 8 KB)

  if (tid < T_SAMP) sidx[tid] = (tid < m) ? lists[c * BATCH + base + tid] : -1;
  __syncthreads();

  const int nbase = zn * NCHUNK;
  const int dbase = zd * DSLICE;

  // wave-uniform E base (per-lane offset added inside STAGE)
  const float* Eb = E + (size_t)c * (N_EMB * DIM) + (size_t)nbase * DIM + dbase;

  // Wave sg stages rows sg*2, sg*2+1 of chunk CK into ebuf[NB]
#define STAGE(NB, CK)                                                          \
  {                                                                            \
    const float* g0 = Eb + (size_t)((CK) * RCHUNK + sg * 2) * DIM + lane * 4;  \
    __builtin_amdgcn_global_load_lds(                                          \
        (const __attribute__((address_space(1))) unsigned int*)g0,             \
        (__attribute__((address_space(3))) unsigned int*)&ebuf[NB][sg * 2][0], \
        16, 0, 0);                                                             \
    const float* g1 = g0 + DIM;                                                \
    __builtin_amdgcn_global_load_lds(                                          \
        (const __attribute__((address_space(1))) unsigned int*)g1,             \
        (__attribute__((address_space(3))) unsigned int*)&ebuf[NB][sg * 2 + 1][0], \
        16, 0, 0);                                                             \
  }

  STAGE(0, 0);  // chunk-0 DMA overlaps the weight fill below

  // fill weight slice: 48 samples x 64 rows = 3072 = 12 x 256 (coalesced)
#pragma unroll
  for (int k = 0; k < 12; ++k) {
    const int idx = tid + k * 256;
    const int t = idx >> 6;          // sample 0..47
    const int j = idx & (NCHUNK - 1);
    const int s = sidx[t];
    wlT[j][t] = (s >= 0) ? W[(size_t)s * N_EMB + nbase + j] : 0.0f;
  }

  float4 a0 = make_float4(0.f, 0.f, 0.f, 0.f);
  float4 a1 = a0, a2 = a0, a3 = a0, a4 = a0, a5 = a0;
  float4 a6 = a0, a7 = a0, a8 = a0, a9 = a0, a10 = a0, a11 = a0;

#define FMA4(ACC, WS)                 \
  ACC.x = fmaf(WS, e.x, ACC.x);       \
  ACC.y = fmaf(WS, e.y, ACC.y);       \
  ACC.z = fmaf(WS, e.z, ACC.z);       \
  ACC.w = fmaf(WS, e.w, ACC.w);

  __syncthreads();  // drains chunk-0 DMA (implicit vmcnt(0)) + publishes wlT

  int cur = 0;
#pragma unroll 1
  for (int ck = 0; ck < NCHUNKS; ++ck) {
    if (ck + 1 < NCHUNKS) STAGE(cur ^ 1, ck + 1);   // async next-chunk DMA
#pragma unroll
    for (int r = 0; r < RCHUNK; ++r) {
      const float4 e = *(const float4*)&ebuf[cur][r][lane * 4];
      const float* wr = &wlT[ck * RCHUNK + r][sb];
      const float4 w0 = *(const float4*)(wr + 0);   // broadcast reads
      const float4 w1 = *(const float4*)(wr + 4);
      const float4 w2 = *(const float4*)(wr + 8);
      FMA4(a0, w0.x) FMA4(a1, w0.y) FMA4(a2, w0.z) FMA4(a3, w0.w)
      FMA4(a4, w1.x) FMA4(a5, w1.y) FMA4(a6, w1.z) FMA4(a7, w1.w)
      FMA4(a8, w2.x) FMA4(a9, w2.y) FMA4(a10, w2.z) FMA4(a11, w2.w)
    }
    __syncthreads();  // next buf ready + cur safe to overwrite
    cur ^= 1;
  }
#undef FMA4
#undef STAGE

  float* Pz = P + (size_t)zn * (BATCH * DIM) + dbase + lane * 4;
#define PSTORE(K, ACC) \
  if (sb + K < m) *(float4*)(Pz + (size_t)sidx[sb + K] * DIM) = ACC;
  PSTORE(0, a0) PSTORE(1, a1) PSTORE(2, a2) PSTORE(3, a3)
  PSTORE(4, a4) PSTORE(5, a5) PSTORE(6, a6) PSTORE(7, a7)
  PSTORE(8, a8) PSTORE(9, a9) PSTORE(10, a10) PSTORE(11, a11)
#undef PSTORE
}

// ---------------- Kernel 3: sum partials over zn ----------------
__global__ __launch_bounds__(256) void atac_final_reduce(
    const float* __restrict__ P, float* __restrict__ out) {
  const int i = blockIdx.x * 256 + threadIdx.x;  // float4 index
  const float4* p = (const float4*)P;
  float4 s = p[i];
#pragma unroll
  for (int zz = 1; zz < NSPLIT_N; ++zz) {
    const float4 v = p[(size_t)zz * (BATCH * DIM / 4) + i];
    s.x += v.x; s.y += v.y; s.z += v.z; s.w += v.w;
  }
  ((float4*)out)[i] = s;
}

// ---------------- Fallback: fully fused naive (tiny workspace) ----------------
__global__ __launch_bounds__(512) void atac_fused_naive(
    const int* __restrict__ chrom, const float* __restrict__ pos,
    const float* __restrict__ E, const float* __restrict__ centers,
    const float* __restrict__ logvar, float* __restrict__ out) {
  const int b = blockIdx.x;
  const int tid = threadIdx.x;
  const int c = chrom[b];
  const float p = pos[b];
  __shared__ float w[N_EMB];
  __shared__ float red[8];

  const float d = p - centers[(size_t)c * N_EMB + tid];
  const float wv = expf(-(d * d) / (2.0f * expf(logvar[(size_t)c * N_EMB + tid])));
  float s = wv;
#pragma unroll
  for (int off = 32; off > 0; off >>= 1) s += __shfl_down(s, off);
  if ((tid & 63) == 0) red[tid >> 6] = s;
  __syncthreads();
  if (tid == 0) {
    float tot = 0.f;
#pragma unroll
    for (int i = 0; i < 8; ++i) tot += red[i];
    red[0] = 1.0f / tot;
  }
  __syncthreads();
  w[tid] = wv * red[0];
  __syncthreads();

  float acc = 0.f;
  const float* Ec = E + (size_t)c * (N_EMB * DIM) + tid;
  for (int n = 0; n < N_EMB; ++n) acc = fmaf(w[n], Ec[(size_t)n * DIM], acc);
  out[(size_t)b * DIM + tid] = acc;
}

extern "C" void kernel_launch(void* const* d_in, const int* in_sizes, int n_in,
                              void* d_out, int out_size, void* d_ws, size_t ws_size,
                              hipStream_t stream) {
  const int* chrom = (const int*)d_in[0];
  const float* pos = (const float*)d_in[1];
  const float* E = (const float*)d_in[2];
  const float* centers = (const float*)d_in[3];
  const float* logvar = (const float*)d_in[4];
  float* out = (float*)d_out;
  char* ws = (char*)d_ws;

  if (ws_size < OFF_P + (size_t)NSPLIT_N * P_BYTES) {
    atac_fused_naive<<<BATCH, 512, 0, stream>>>(chrom, pos, E, centers, logvar, out);
    return;
  }

  int* counts = (int*)(ws + OFF_COUNTS);
  int* lists = (int*)(ws + OFF_LISTS);
  float* W = (float*)(ws + OFF_W);
  float* P = (float*)(ws + OFF_P);

  hipMemsetAsync(counts, 0, NUM_CHR * sizeof(int), stream);
  atac_weights_kernel<<<BATCH, 256, 0, stream>>>(chrom, pos, centers, logvar, W,
                                                 counts, lists);
  atac_reduce_kernel<<<dim3(NUM_CHR, GROUPS_CAP, NSPLIT_N * DSPLIT), 256, 0, stream>>>(
      E, W, counts, lists, P);
  atac_final_reduce<<<(BATCH * DIM / 4) / 256, 256, 0, stream>>>(P, out);
}